// Round 1
// baseline (434.103 us; speedup 1.0000x reference)
//
#include <hip/hip_runtime.h>
#include <stdint.h>
#include <math.h>

// Order-preserving float -> uint32 encoding: f1 < f2  <=>  enc(f1) < enc(f2)
__device__ __forceinline__ uint32_t enc_f32(float f) {
    uint32_t b = __float_as_uint(f);
    return (b & 0x80000000u) ? ~b : (b | 0x80000000u);
}
__device__ __forceinline__ float dec_f32(uint32_t u) {
    uint32_t b = (u & 0x80000000u) ? (u ^ 0x80000000u) : ~u;
    return __uint_as_float(b);
}

__global__ void init_ws_kernel(uint32_t* ws) {
    // ws[0]: running-min slot (encoded), init to +inf encoding = 0xFFFFFFFF
    // ws[1]: running-max slot (encoded), init to -inf encoding = 0x00000000
    ws[0] = 0xFFFFFFFFu;
    ws[1] = 0x00000000u;
}

__global__ __launch_bounds__(256) void minmax_kernel(
    const float4* __restrict__ x4, long n4,
    const float* __restrict__ x, long n,
    uint32_t* __restrict__ ws)
{
    float mn = INFINITY, mx = -INFINITY;
    const long stride = (long)gridDim.x * blockDim.x;
    for (long i = (long)blockIdx.x * blockDim.x + threadIdx.x; i < n4; i += stride) {
        float4 v = x4[i];
        mn = fminf(mn, fminf(fminf(v.x, v.y), fminf(v.z, v.w)));
        mx = fmaxf(mx, fmaxf(fmaxf(v.x, v.y), fmaxf(v.z, v.w)));
    }
    // scalar tail (n not divisible by 4)
    for (long i = n4 * 4 + (long)blockIdx.x * blockDim.x + threadIdx.x; i < n; i += stride) {
        float v = x[i];
        mn = fminf(mn, v);
        mx = fmaxf(mx, v);
    }
    // wave-64 shuffle reduction
    #pragma unroll
    for (int off = 32; off > 0; off >>= 1) {
        mn = fminf(mn, __shfl_down(mn, off, 64));
        mx = fmaxf(mx, __shfl_down(mx, off, 64));
    }
    __shared__ float smn[4], smx[4];
    const int wave = threadIdx.x >> 6;
    const int lane = threadIdx.x & 63;
    if (lane == 0) { smn[wave] = mn; smx[wave] = mx; }
    __syncthreads();
    if (threadIdx.x == 0) {
        const int nw = blockDim.x >> 6;
        mn = smn[0]; mx = smx[0];
        for (int w = 1; w < nw; ++w) {
            mn = fminf(mn, smn[w]);
            mx = fmaxf(mx, smx[w]);
        }
        atomicMin(&ws[0], enc_f32(mn));   // device-scope by default (G12)
        atomicMax(&ws[1], enc_f32(mx));
    }
}

__global__ __launch_bounds__(256) void quant_kernel(
    const float4* __restrict__ x4, long n4,
    const float* __restrict__ x, long n,
    float4* __restrict__ o4, float* __restrict__ o,
    const uint32_t* __restrict__ ws)
{
    const float mn = dec_f32(ws[0]);
    const float mx = dec_f32(ws[1]);
    const float scale = 255.0f / (mx - mn);
    const float inv_scale = 1.0f / scale;
    const long stride = (long)gridDim.x * blockDim.x;
    for (long i = (long)blockIdx.x * blockDim.x + threadIdx.x; i < n4; i += stride) {
        float4 v = x4[i];
        float4 r;
        // clip(x, mn, mx) is a no-op: mn/mx are exact global extrema of x.
        // rintf -> v_rndne_f32 (round-half-to-even), matches jnp.round.
        r.x = rintf((v.x - mn) * scale) * inv_scale + mn;
        r.y = rintf((v.y - mn) * scale) * inv_scale + mn;
        r.z = rintf((v.z - mn) * scale) * inv_scale + mn;
        r.w = rintf((v.w - mn) * scale) * inv_scale + mn;
        o4[i] = r;
    }
    for (long i = n4 * 4 + (long)blockIdx.x * blockDim.x + threadIdx.x; i < n; i += stride) {
        o[i] = rintf((x[i] - mn) * scale) * inv_scale + mn;
    }
}

extern "C" void kernel_launch(void* const* d_in, const int* in_sizes, int n_in,
                              void* d_out, int out_size, void* d_ws, size_t ws_size,
                              hipStream_t stream) {
    const float* x = (const float*)d_in[0];
    float* out = (float*)d_out;
    const long n = (long)in_sizes[0];
    const long n4 = n / 4;
    uint32_t* ws = (uint32_t*)d_ws;

    init_ws_kernel<<<1, 1, 0, stream>>>(ws);

    // 4096 blocks x 256 threads: 1M threads, ~12 float4 each at n=51.4M.
    // Streaming grid-stride, consecutive lanes -> consecutive float4 (coalesced).
    const int block = 256;
    const int grid = 4096;
    minmax_kernel<<<grid, block, 0, stream>>>((const float4*)x, n4, x, n, ws);
    quant_kernel<<<grid, block, 0, stream>>>((const float4*)x, n4, x, n,
                                             (float4*)out, out, ws);
}

// Round 3
// 376.019 us; speedup vs baseline: 1.1545x; 1.1545x over previous
//
#include <hip/hip_runtime.h>
#include <stdint.h>
#include <math.h>

// Native 16-byte vector type — __builtin_nontemporal_{load,store} requires a
// native vector, not HIP's float4 class.
typedef float vf4 __attribute__((ext_vector_type(4)));

// Order-preserving float -> uint32 encoding: f1 < f2  <=>  enc(f1) < enc(f2)
__device__ __forceinline__ uint32_t enc_f32(float f) {
    uint32_t b = __float_as_uint(f);
    return (b & 0x80000000u) ? ~b : (b | 0x80000000u);
}
__device__ __forceinline__ float dec_f32(uint32_t u) {
    uint32_t b = (u & 0x80000000u) ? (u ^ 0x80000000u) : ~u;
    return __uint_as_float(b);
}

__global__ void init_ws_kernel(uint32_t* ws) {
    ws[0] = 0xFFFFFFFFu;  // +inf encoded (running min slot)
    ws[1] = 0x00000000u;  // -inf encoded (running max slot)
}

__device__ __forceinline__ void mm4(vf4 v, float& mn, float& mx) {
    mn = fminf(mn, fminf(fminf(v.x, v.y), fminf(v.z, v.w)));
    mx = fmaxf(mx, fmaxf(fmaxf(v.x, v.y), fmaxf(v.z, v.w)));
}

// 4x-unrolled min/max reduction: 4 independent 16B loads in flight per thread
// per iteration (64 B). Independent accumulators keep the loads' dest
// registers disjoint so the compiler can't fold back to vmcnt(0)/iter.
__global__ __launch_bounds__(256) void minmax_kernel(
    const vf4* __restrict__ x4, unsigned n4,
    uint32_t* __restrict__ ws)
{
    float mn0 = INFINITY, mn1 = INFINITY, mn2 = INFINITY, mn3 = INFINITY;
    float mx0 = -INFINITY, mx1 = -INFINITY, mx2 = -INFINITY, mx3 = -INFINITY;

    const unsigned bs = blockDim.x;                    // 256
    const unsigned stride = gridDim.x * bs * 4u;       // vf4 elements per iter
    unsigned base = blockIdx.x * bs * 4u + threadIdx.x;

    for (; base + 3u * bs < n4; base += stride) {
        vf4 v0 = x4[base];
        vf4 v1 = x4[base + bs];
        vf4 v2 = x4[base + 2u * bs];
        vf4 v3 = x4[base + 3u * bs];
        mm4(v0, mn0, mx0);
        mm4(v1, mn1, mx1);
        mm4(v2, mn2, mx2);
        mm4(v3, mn3, mx3);
    }
    for (; base < n4; base += bs) {
        mm4(x4[base], mn0, mx0);
    }

    float mn = fminf(fminf(mn0, mn1), fminf(mn2, mn3));
    float mx = fmaxf(fmaxf(mx0, mx1), fmaxf(mx2, mx3));

    #pragma unroll
    for (int off = 32; off > 0; off >>= 1) {
        mn = fminf(mn, __shfl_down(mn, off, 64));
        mx = fmaxf(mx, __shfl_down(mx, off, 64));
    }
    __shared__ float smn[4], smx[4];
    const int wave = threadIdx.x >> 6;
    const int lane = threadIdx.x & 63;
    if (lane == 0) { smn[wave] = mn; smx[wave] = mx; }
    __syncthreads();
    if (threadIdx.x == 0) {
        mn = fminf(fminf(smn[0], smn[1]), fminf(smn[2], smn[3]));
        mx = fmaxf(fmaxf(smx[0], smx[1]), fmaxf(smx[2], smx[3]));
        atomicMin(&ws[0], enc_f32(mn));
        atomicMax(&ws[1], enc_f32(mx));
    }
}

__device__ __forceinline__ vf4 q4(vf4 v, float mn, float scale, float inv_scale) {
    vf4 r;
    r.x = rintf((v.x - mn) * scale) * inv_scale + mn;
    r.y = rintf((v.y - mn) * scale) * inv_scale + mn;
    r.z = rintf((v.z - mn) * scale) * inv_scale + mn;
    r.w = rintf((v.w - mn) * scale) * inv_scale + mn;
    return r;
}

__global__ __launch_bounds__(256) void quant_kernel(
    const vf4* __restrict__ x4, unsigned n4,
    vf4* __restrict__ o4,
    const uint32_t* __restrict__ ws)
{
    const float mn = dec_f32(ws[0]);
    const float mx = dec_f32(ws[1]);
    const float scale = 255.0f / (mx - mn);
    const float inv_scale = 1.0f / scale;

    const unsigned bs = blockDim.x;
    const unsigned stride = gridDim.x * bs * 4u;
    unsigned base = blockIdx.x * bs * 4u + threadIdx.x;

    for (; base + 3u * bs < n4; base += stride) {
        vf4 v0 = x4[base];
        vf4 v1 = x4[base + bs];
        vf4 v2 = x4[base + 2u * bs];
        vf4 v3 = x4[base + 3u * bs];
        // Output is written once and never re-read: stream it past the caches
        // so the input (hot in L3 from pass 1) isn't evicted by write-allocate.
        __builtin_nontemporal_store(q4(v0, mn, scale, inv_scale), &o4[base]);
        __builtin_nontemporal_store(q4(v1, mn, scale, inv_scale), &o4[base + bs]);
        __builtin_nontemporal_store(q4(v2, mn, scale, inv_scale), &o4[base + 2u * bs]);
        __builtin_nontemporal_store(q4(v3, mn, scale, inv_scale), &o4[base + 3u * bs]);
    }
    for (; base < n4; base += bs) {
        __builtin_nontemporal_store(q4(x4[base], mn, scale, inv_scale), &o4[base]);
    }
}

// Scalar-remainder cleanup (n % 4 != 0) — not hit for this problem's shape
// (51,380,224 % 4 == 0) but kept for generality.
__global__ void quant_tail_kernel(const float* __restrict__ x, long start, long n,
                                  float* __restrict__ o,
                                  const uint32_t* __restrict__ ws)
{
    const float mn = dec_f32(ws[0]);
    const float mx = dec_f32(ws[1]);
    const float scale = 255.0f / (mx - mn);
    const float inv_scale = 1.0f / scale;
    long i = start + threadIdx.x;
    if (i < n) o[i] = rintf((x[i] - mn) * scale) * inv_scale + mn;
}

__global__ void minmax_tail_kernel(const float* __restrict__ x, long start, long n,
                                   uint32_t* __restrict__ ws)
{
    long i = start + threadIdx.x;
    if (i < n) {
        float v = x[i];
        atomicMin(&ws[0], enc_f32(v));
        atomicMax(&ws[1], enc_f32(v));
    }
}

extern "C" void kernel_launch(void* const* d_in, const int* in_sizes, int n_in,
                              void* d_out, int out_size, void* d_ws, size_t ws_size,
                              hipStream_t stream) {
    const float* x = (const float*)d_in[0];
    float* out = (float*)d_out;
    const long n = (long)in_sizes[0];
    const unsigned n4 = (unsigned)(n / 4);
    uint32_t* ws = (uint32_t*)d_ws;

    init_ws_kernel<<<1, 1, 0, stream>>>(ws);

    const int block = 256;
    const int grid = 2048;  // 8192 waves -> 32/CU; each thread ~6 iters of 64 B

    minmax_kernel<<<grid, block, 0, stream>>>((const vf4*)x, n4, ws);
    if (n % 4) minmax_tail_kernel<<<1, 256, 0, stream>>>(x, (long)n4 * 4, n, ws);

    quant_kernel<<<grid, block, 0, stream>>>((const vf4*)x, n4, (vf4*)out, ws);
    if (n % 4) quant_tail_kernel<<<1, 256, 0, stream>>>(x, (long)n4 * 4, n, out, ws);
}